// Round 5
// baseline (1219.340 us; speedup 1.0000x reference)
//
#include <hip/hip_runtime.h>
#include <hip/hip_bf16.h>

#define NODES 100000
#define EDGES 1600000
#define NGRAPH 512

using bf16 = __hip_bfloat16;
typedef long long ll;

__device__ __forceinline__ float lrelu(float v) { return v > 0.0f ? v : 0.2f * v; }

// monotone float<->uint mapping for atomicMax on floats (handles negatives)
__device__ __forceinline__ unsigned mapf(float f) {
    unsigned u = __float_as_uint(f);
    return (u & 0x80000000u) ? ~u : (u | 0x80000000u);
}
__device__ __forceinline__ float unmapf(unsigned u) {
    return __uint_as_float((u & 0x80000000u) ? (u ^ 0x80000000u) : ~u);
}

// int32/int64 agnostic index read (f=1 -> int64 storage)
__device__ __forceinline__ int idx_at(const void* raw, int i, int f) {
    return f ? (int)((const ll*)raw)[i] : ((const int*)raw)[i];
}

__device__ __forceinline__ float feat_at(const float* p, int i) { return p[i]; }
__device__ __forceinline__ float feat_at(const bf16* p, int i) { return __bfloat162float(p[i]); }

__global__ void detect_int64(const int* __restrict__ w, int* __restrict__ flag) {
    __shared__ int red[4];
    int t = threadIdx.x;
    int v = 0;
    for (int i = t; i < 4096; i += 256) v |= w[2 * i + 1];
    for (int o = 32; o; o >>= 1) v |= __shfl_xor(v, o);
    if ((t & 63) == 0) red[t >> 6] = v;
    __syncthreads();
    if (t == 0) flag[0] = ((red[0] | red[1] | red[2] | red[3]) == 0) ? 1 : 0;
}

// ---- diagnostics ----
__global__ void sentinel_kernel(float* out, float v) {
    int i = blockIdx.x * blockDim.x + threadIdx.x;
    if (i < NGRAPH * 10) out[i] = v;
}

__global__ void audit_f32(const float* __restrict__ p, int n, unsigned bit,
                          unsigned* __restrict__ aud) {
    int stride = gridDim.x * blockDim.x;
    unsigned bad = 0;
    for (int i = blockIdx.x * blockDim.x + threadIdx.x; i < n; i += stride) {
        float v = p[i];
        if (!(fabsf(v) < 1e38f)) { bad = bit; break; }
    }
    if (bad) atomicOr(aud, bad);
}

__global__ void audit_bf16(const unsigned short* __restrict__ p, int n, unsigned bit,
                           unsigned* __restrict__ aud) {
    int stride = gridDim.x * blockDim.x;
    unsigned bad = 0;
    for (int i = blockIdx.x * blockDim.x + threadIdx.x; i < n; i += stride) {
        if ((p[i] & 0x7F80u) == 0x7F80u) { bad = bit; break; }  // inf/NaN bf16
    }
    if (bad) atomicOr(aud, bad);
}

__global__ void audit_pooled(const unsigned* __restrict__ p, int n, unsigned bit,
                             unsigned* __restrict__ aud) {
    int i = blockIdx.x * blockDim.x + threadIdx.x;
    if (i < n) {
        float v = unmapf(p[i]);
        if (!(fabsf(v) < 1e38f)) atomicOr(aud, bit);
    }
}
// ---------------------

__global__ void pooled_init(unsigned* pooled) {
    int i = blockIdx.x * blockDim.x + threadIdx.x;
    if (i < NGRAPH * 64) pooled[i] = mapf(-1e4f);  // finite sentinel
}

__global__ void degree_kernel(const void* __restrict__ ei, const int* __restrict__ flag,
                              float* __restrict__ deg) {
    int i = blockIdx.x * blockDim.x + threadIdx.x;
    if (i >= EDGES) return;
    int d = idx_at(ei, EDGES + i, flag[0]);
    if ((unsigned)d < NODES) atomicAdd(&deg[d], 1.0f);
}

__global__ void dinv_kernel(const float* __restrict__ deg, float* __restrict__ dinv1,
                            float* __restrict__ dinv2) {
    int i = blockIdx.x * blockDim.x + threadIdx.x;
    if (i < NODES) {
        float c = deg[i];
        dinv1[i] = 1.0f / sqrtf(c + 2.0f);
        dinv2[i] = 1.0f / sqrtf(c + 1.0f);
    }
}

// one wave per edge: agg[d] += feat[s] * dinv[s]*dinv[d]
template <typename T>
__global__ void scatter_edges(const T* __restrict__ feat, const void* __restrict__ ei,
                              const int* __restrict__ flag, const float* __restrict__ dinv,
                              float* __restrict__ agg) {
    int tid = blockIdx.x * blockDim.x + threadIdx.x;
    int e = tid >> 6, c = tid & 63;
    if (e >= EDGES) return;
    int f = flag[0];
    int s = idx_at(ei, e, f), d = idx_at(ei, EDGES + e, f);
    if ((unsigned)s >= NODES || (unsigned)d >= NODES) return;
    float nrm = dinv[s] * dinv[d];
    atomicAdd(&agg[d * 64 + c], feat_at(feat, s * 64 + c) * nrm);
}

// layer1 epilogue: v = agg + 2*dinv^2*x; y = v@W1 + b1; LN; leaky -> h1 (bf16)
__global__ void epilogue1(const float* __restrict__ agg, const float* __restrict__ x,
                          const float* __restrict__ dinv, const float* __restrict__ W1,
                          const float* __restrict__ b1, const float* __restrict__ lng,
                          const float* __restrict__ lnb, bf16* __restrict__ h1) {
    __shared__ float Wl[64 * 64];
    int t = threadIdx.x;
    for (int i = t; i < 64 * 64; i += 256) Wl[i] = W1[i];
    __syncthreads();
    int lane = t & 63, wave = t >> 6;
    for (int row = blockIdx.x * 4 + wave; row < NODES; row += gridDim.x * 4) {
        float dv = dinv[row];
        float v = agg[row * 64 + lane] + 2.0f * dv * dv * x[row * 64 + lane];
        float acc = b1[lane];
#pragma unroll
        for (int k = 0; k < 64; ++k) acc += __shfl(v, k) * Wl[k * 64 + lane];
        float s = acc;
        for (int o = 32; o; o >>= 1) s += __shfl_xor(s, o);
        float mu = s * (1.0f / 64.0f);
        float d = acc - mu;
        float q = d * d;
        for (int o = 32; o; o >>= 1) q += __shfl_xor(q, o);
        float var = q * (1.0f / 64.0f);
        float y = d / sqrtf(var + 1e-5f) * lng[lane] + lnb[lane];
        h1[row * 64 + lane] = __float2bfloat16(lrelu(y));
    }
}

// layer2 epilogue: v = agg + dinv^2*h1; z = v@W2 + b2; leaky; fused max-pool
__global__ void epilogue2(const float* __restrict__ agg, const bf16* __restrict__ h1,
                          const float* __restrict__ dinv, const float* __restrict__ W2,
                          const float* __restrict__ b2, const void* __restrict__ batch,
                          const int* __restrict__ flag, unsigned* __restrict__ pooled) {
    __shared__ float Wl[64 * 64];
    int t = threadIdx.x;
    for (int i = t; i < 64 * 64; i += 256) Wl[i] = W2[i];
    __syncthreads();
    int lane = t & 63, wave = t >> 6;
    int f = flag[0];
    for (int row = blockIdx.x * 4 + wave; row < NODES; row += gridDim.x * 4) {
        float dv = dinv[row];
        float v = agg[row * 64 + lane] + dv * dv * __bfloat162float(h1[row * 64 + lane]);
        float acc = b2[lane];
#pragma unroll
        for (int k = 0; k < 64; ++k) acc += __shfl(v, k) * Wl[k * 64 + lane];
        acc = lrelu(acc);
        int g = idx_at(batch, row, f);
        if ((unsigned)g < NGRAPH) atomicMax(&pooled[g * 64 + lane], mapf(acc));
    }
}

// head: z = pooled@W3+b3; LN; leaky; z@W4+b4; softmax. One block per graph.
__global__ void head_kernel(const unsigned* __restrict__ pooled, const float* __restrict__ W3,
                            const float* __restrict__ b3, const float* __restrict__ g2,
                            const float* __restrict__ be2, const float* __restrict__ W4,
                            const float* __restrict__ b4, const unsigned* __restrict__ aud,
                            float* __restrict__ out) {
    int t = threadIdx.x, gI = blockIdx.x;
    unsigned a = aud[0];
    if (a != 0) {  // diagnostic: encode first-poisoned-stage in the output
        if (t == 0)
            for (int c = 0; c < 10; ++c) out[gI * 10 + c] = 2.0f + (float)a;
        return;
    }
    __shared__ float prow[64];
    __shared__ float z[768];
    __shared__ float rs[4], rss[4];
    __shared__ float mu_s, rstd_s;
    __shared__ float red[10];
    if (t < 64) prow[t] = unmapf(pooled[gI * 64 + t]);
    __syncthreads();
    for (int c = t; c < 768; c += 256) {
        float acc = b3[c];
#pragma unroll 16
        for (int k = 0; k < 64; ++k) acc += prow[k] * W3[k * 768 + c];
        z[c] = acc;
    }
    __syncthreads();
    float s = 0.0f, ss = 0.0f;
    for (int c = t; c < 768; c += 256) {
        float v = z[c];
        s += v;
        ss += v * v;
    }
    for (int o = 32; o; o >>= 1) {
        s += __shfl_xor(s, o);
        ss += __shfl_xor(ss, o);
    }
    if ((t & 63) == 0) { rs[t >> 6] = s; rss[t >> 6] = ss; }
    __syncthreads();
    if (t == 0) {
        float S = rs[0] + rs[1] + rs[2] + rs[3];
        float SS = rss[0] + rss[1] + rss[2] + rss[3];
        float mu = S * (1.0f / 768.0f);
        float var = SS * (1.0f / 768.0f) - mu * mu;
        mu_s = mu;
        rstd_s = 1.0f / sqrtf(fmaxf(var, 0.0f) + 1e-5f);
    }
    __syncthreads();
    for (int c = t; c < 768; c += 256) {
        float y = (z[c] - mu_s) * rstd_s * g2[c] + be2[c];
        z[c] = lrelu(y);
    }
    if (t < 10) red[t] = 0.0f;
    __syncthreads();
    float p[10];
#pragma unroll
    for (int c = 0; c < 10; ++c) p[c] = 0.0f;
    for (int k = t; k < 768; k += 256) {
        float zv = z[k];
#pragma unroll
        for (int c = 0; c < 10; ++c) p[c] += zv * W4[k * 10 + c];
    }
#pragma unroll
    for (int c = 0; c < 10; ++c) atomicAdd(&red[c], p[c]);
    __syncthreads();
    if (t == 0) {
        float l[10], m = -1e30f;
#pragma unroll
        for (int c = 0; c < 10; ++c) {
            l[c] = red[c] + b4[c];
            m = fmaxf(m, l[c]);
        }
        float sum = 0.0f;
#pragma unroll
        for (int c = 0; c < 10; ++c) {
            l[c] = expf(l[c] - m);
            sum += l[c];
        }
        float inv = 1.0f / sum;
#pragma unroll
        for (int c = 0; c < 10; ++c) out[gI * 10 + c] = l[c] * inv;
    }
}

extern "C" void kernel_launch(void* const* d_in, const int* in_sizes, int n_in,
                              void* d_out, int out_size, void* d_ws, size_t ws_size,
                              hipStream_t stream) {
    const size_t REQUIRED = (size_t)NODES * 64 * 4      // agg
                          + (size_t)NODES * 64 * 2      // h1 (bf16)
                          + (size_t)NODES * 4 * 3       // deg, dinv1, dinv2
                          + (size_t)NGRAPH * 64 * 4     // pooled
                          + 16;                         // flag + aud
    if (ws_size < REQUIRED) {
        sentinel_kernel<<<20, 256, 0, stream>>>((float*)d_out, 64.0f);
        return;
    }

    const float* x = (const float*)d_in[0];
    const void* ei = d_in[1];
    const void* batch = d_in[2];
    const float* W1 = (const float*)d_in[3];
    const float* b1 = (const float*)d_in[4];
    const float* lng = (const float*)d_in[5];
    const float* lnb = (const float*)d_in[6];
    const float* W2 = (const float*)d_in[7];
    const float* b2 = (const float*)d_in[8];
    const float* W3 = (const float*)d_in[9];
    const float* b3 = (const float*)d_in[10];
    const float* g2 = (const float*)d_in[11];
    const float* be2 = (const float*)d_in[12];
    const float* W4 = (const float*)d_in[13];
    const float* b4 = (const float*)d_in[14];

    float* wsp = (float*)d_ws;
    float* agg = wsp;                                     // N*64 fp32
    bf16* h1 = (bf16*)(agg + (size_t)NODES * 64);         // N*64 bf16
    float* deg = (float*)(h1 + (size_t)NODES * 64);       // N
    float* dinv1 = deg + NODES;                           // N
    float* dinv2 = dinv1 + NODES;                         // N
    unsigned* pooled = (unsigned*)(dinv2 + NODES);        // G*64
    int* flag = (int*)(pooled + NGRAPH * 64);             // flag[0]=int64?, aud
    unsigned* aud = (unsigned*)(flag + 1);

    hipMemsetAsync(flag, 0, 8, stream);
    detect_int64<<<1, 256, 0, stream>>>((const int*)ei, flag);
    hipMemsetAsync(deg, 0, (size_t)NODES * 4, stream);
    hipMemsetAsync(agg, 0, (size_t)NODES * 64 * 4, stream);
    pooled_init<<<(NGRAPH * 64 + 255) / 256, 256, 0, stream>>>(pooled);

    audit_f32<<<1024, 256, 0, stream>>>(x, NODES * 64, 1u << 4, aud);

    degree_kernel<<<(EDGES + 255) / 256, 256, 0, stream>>>(ei, flag, deg);
    dinv_kernel<<<(NODES + 255) / 256, 256, 0, stream>>>(deg, dinv1, dinv2);

    // layer 1
    scatter_edges<float><<<(EDGES * 64) / 256, 256, 0, stream>>>(x, ei, flag, dinv1, agg);
    audit_f32<<<1024, 256, 0, stream>>>(agg, NODES * 64, 1u << 0, aud);
    epilogue1<<<2048, 256, 0, stream>>>(agg, x, dinv1, W1, b1, lng, lnb, h1);
    audit_bf16<<<1024, 256, 0, stream>>>((const unsigned short*)h1, NODES * 64, 1u << 1, aud);

    // layer 2
    hipMemsetAsync(agg, 0, (size_t)NODES * 64 * 4, stream);
    scatter_edges<bf16><<<(EDGES * 64) / 256, 256, 0, stream>>>(h1, ei, flag, dinv2, agg);
    audit_f32<<<1024, 256, 0, stream>>>(agg, NODES * 64, 1u << 2, aud);
    epilogue2<<<2048, 256, 0, stream>>>(agg, h1, dinv2, W2, b2, batch, flag, pooled);
    audit_pooled<<<(NGRAPH * 64 + 255) / 256, 256, 0, stream>>>(pooled, NGRAPH * 64, 1u << 3, aud);

    // head
    head_kernel<<<NGRAPH, 256, 0, stream>>>(pooled, W3, b3, g2, be2, W4, b4, aud,
                                            (float*)d_out);
}

// Round 6
// 785.846 us; speedup vs baseline: 1.5516x; 1.5516x over previous
//
#include <hip/hip_runtime.h>
#include <hip/hip_bf16.h>

#define NODES 100000
#define EDGES 1600000
#define NGRAPH 512
#define NTILES 98  // ceil(100001 / 1024)

using bf16 = __hip_bfloat16;
typedef long long ll;

__device__ __forceinline__ float lrelu(float v) { return v > 0.0f ? v : 0.2f * v; }

// monotone float<->uint mapping for atomicMax on floats (handles negatives)
__device__ __forceinline__ unsigned mapf(float f) {
    unsigned u = __float_as_uint(f);
    return (u & 0x80000000u) ? ~u : (u | 0x80000000u);
}
__device__ __forceinline__ float unmapf(unsigned u) {
    return __uint_as_float((u & 0x80000000u) ? (u ^ 0x80000000u) : ~u);
}

// int32/int64 agnostic index read (f=1 -> int64 storage)
__device__ __forceinline__ int idx_at(const void* raw, int i, int f) {
    return f ? (int)((const ll*)raw)[i] : ((const int*)raw)[i];
}

__global__ void detect_int64(const int* __restrict__ w, int* __restrict__ flag) {
    __shared__ int red[4];
    int t = threadIdx.x;
    int v = 0;
    for (int i = t; i < 4096; i += 256) v |= w[2 * i + 1];
    for (int o = 32; o; o >>= 1) v |= __shfl_xor(v, o);
    if ((t & 63) == 0) red[t >> 6] = v;
    __syncthreads();
    if (t == 0) flag[0] = ((red[0] | red[1] | red[2] | red[3]) == 0) ? 1 : 0;
}

__global__ void sentinel_kernel(float* out, float v) {
    int i = blockIdx.x * blockDim.x + threadIdx.x;
    if (i < NGRAPH * 10) out[i] = v;
}

__global__ void pooled_init(unsigned* pooled) {
    int i = blockIdx.x * blockDim.x + threadIdx.x;
    if (i < NGRAPH * 64) pooled[i] = mapf(-1e4f);
}

// int degree histogram over dst
__global__ void degree_kernel(const void* __restrict__ ei, const int* __restrict__ flag,
                              int* __restrict__ deg) {
    int i = blockIdx.x * blockDim.x + threadIdx.x;
    if (i >= EDGES) return;
    int d = idx_at(ei, EDGES + i, flag[0]);
    if ((unsigned)d < NODES) atomicAdd(&deg[d], 1);
}

__global__ void dinv_kernel(const int* __restrict__ deg, float* __restrict__ dinv1,
                            float* __restrict__ dinv2) {
    int i = blockIdx.x * blockDim.x + threadIdx.x;
    if (i < NODES) {
        float c = (float)deg[i];
        dinv1[i] = 1.0f / sqrtf(c + 2.0f);
        dinv2[i] = 1.0f / sqrtf(c + 1.0f);
    }
}

// ---- exclusive scan of deg -> row_ptr (3-phase) ----
__global__ void scanA(const int* __restrict__ deg, int* __restrict__ blocksum) {
    __shared__ int red[4];
    int b = blockIdx.x, t = threadIdx.x;
    int base = b * 1024;
    int s = 0;
#pragma unroll
    for (int k = 0; k < 4; ++k) {
        int i = base + t + k * 256;
        if (i < NODES) s += deg[i];
    }
    for (int o = 32; o; o >>= 1) s += __shfl_xor(s, o);
    if ((t & 63) == 0) red[t >> 6] = s;
    __syncthreads();
    if (t == 0) blocksum[b] = red[0] + red[1] + red[2] + red[3];
}

__global__ void scanB(const int* __restrict__ blocksum, int* __restrict__ blockoff) {
    if (threadIdx.x == 0) {
        int acc = 0;
        for (int b = 0; b < NTILES; ++b) {
            blockoff[b] = acc;
            acc += blocksum[b];
        }
    }
}

__global__ void scanC(const int* __restrict__ deg, const int* __restrict__ blockoff,
                      int* __restrict__ row_ptr) {
    __shared__ int sc[256];
    int b = blockIdx.x, t = threadIdx.x;
    int base = b * 1024 + t * 4;
    int v[4];
#pragma unroll
    for (int k = 0; k < 4; ++k) {
        int i = base + k;
        v[k] = (i < NODES) ? deg[i] : 0;
    }
    int tsum = v[0] + v[1] + v[2] + v[3];
    sc[t] = tsum;
    __syncthreads();
    for (int o = 1; o < 256; o <<= 1) {
        int u = (t >= o) ? sc[t - o] : 0;
        __syncthreads();
        sc[t] += u;
        __syncthreads();
    }
    int excl = sc[t] - tsum + blockoff[b];
#pragma unroll
    for (int k = 0; k < 4; ++k) {
        int i = base + k;
        if (i <= NODES) row_ptr[i] = excl;
        excl += v[k];
    }
}
// ----------------------------------------------------

__global__ void fill_csr(const void* __restrict__ ei, const int* __restrict__ flag,
                         const int* __restrict__ row_ptr, int* __restrict__ cursor,
                         int* __restrict__ csr_src) {
    int i = blockIdx.x * blockDim.x + threadIdx.x;
    if (i >= EDGES) return;
    int f = flag[0];
    int s = idx_at(ei, i, f), d = idx_at(ei, EDGES + i, f);
    if ((unsigned)s >= NODES || (unsigned)d >= NODES) return;
    int slot = row_ptr[d] + atomicAdd(&cursor[d], 1);
    csr_src[slot] = s;
}

// fused layer1: CSR gather + self-loop + @W1 + b1 + LN + leaky -> h1 (bf16)
__global__ void gcn1_fused(const float* __restrict__ x, const int* __restrict__ csr,
                           const int* __restrict__ rp, const float* __restrict__ dinv,
                           const float* __restrict__ W1, const float* __restrict__ b1,
                           const float* __restrict__ lng, const float* __restrict__ lnb,
                           bf16* __restrict__ h1) {
    __shared__ float Wl[64 * 64];
    int t = threadIdx.x;
    for (int i = t; i < 64 * 64; i += 256) Wl[i] = W1[i];
    __syncthreads();
    int lane = t & 63, wave = t >> 6;
    for (int row = blockIdx.x * 4 + wave; row < NODES; row += gridDim.x * 4) {
        int beg = rp[row], end = rp[row + 1];
        float acc0 = 0.0f, acc1 = 0.0f;
        int j = beg;
        for (; j + 1 < end; j += 2) {
            int s0 = csr[j], s1 = csr[j + 1];
            float w0 = dinv[s0], w1 = dinv[s1];
            acc0 += x[(size_t)s0 * 64 + lane] * w0;
            acc1 += x[(size_t)s1 * 64 + lane] * w1;
        }
        if (j < end) {
            int s0 = csr[j];
            acc0 += x[(size_t)s0 * 64 + lane] * dinv[s0];
        }
        float dv = dinv[row];
        float v = (acc0 + acc1) * dv + 2.0f * dv * dv * x[(size_t)row * 64 + lane];
        float a = b1[lane];
#pragma unroll
        for (int k = 0; k < 64; ++k) a += __shfl(v, k) * Wl[k * 64 + lane];
        float s = a;
        for (int o = 32; o; o >>= 1) s += __shfl_xor(s, o);
        float mu = s * (1.0f / 64.0f);
        float d = a - mu;
        float q = d * d;
        for (int o = 32; o; o >>= 1) q += __shfl_xor(q, o);
        float var = q * (1.0f / 64.0f);
        float y = d / sqrtf(var + 1e-5f) * lng[lane] + lnb[lane];
        h1[(size_t)row * 64 + lane] = __float2bfloat16(lrelu(y));
    }
}

// fused layer2: CSR gather (bf16 h1) + self-loop + @W2 + b2 + leaky + max-pool
__global__ void gcn2_fused(const bf16* __restrict__ h1, const int* __restrict__ csr,
                           const int* __restrict__ rp, const float* __restrict__ dinv,
                           const float* __restrict__ W2, const float* __restrict__ b2,
                           const void* __restrict__ batch, const int* __restrict__ flag,
                           unsigned* __restrict__ pooled) {
    __shared__ float Wl[64 * 64];
    int t = threadIdx.x;
    for (int i = t; i < 64 * 64; i += 256) Wl[i] = W2[i];
    __syncthreads();
    int lane = t & 63, wave = t >> 6;
    int f = flag[0];
    for (int row = blockIdx.x * 4 + wave; row < NODES; row += gridDim.x * 4) {
        int beg = rp[row], end = rp[row + 1];
        float acc0 = 0.0f, acc1 = 0.0f;
        int j = beg;
        for (; j + 1 < end; j += 2) {
            int s0 = csr[j], s1 = csr[j + 1];
            float w0 = dinv[s0], w1 = dinv[s1];
            acc0 += __bfloat162float(h1[(size_t)s0 * 64 + lane]) * w0;
            acc1 += __bfloat162float(h1[(size_t)s1 * 64 + lane]) * w1;
        }
        if (j < end) {
            int s0 = csr[j];
            acc0 += __bfloat162float(h1[(size_t)s0 * 64 + lane]) * dinv[s0];
        }
        float dv = dinv[row];
        float v = (acc0 + acc1) * dv +
                  dv * dv * __bfloat162float(h1[(size_t)row * 64 + lane]);
        float a = b2[lane];
#pragma unroll
        for (int k = 0; k < 64; ++k) a += __shfl(v, k) * Wl[k * 64 + lane];
        a = lrelu(a);
        int g = idx_at(batch, row, f);
        if ((unsigned)g < NGRAPH) atomicMax(&pooled[g * 64 + lane], mapf(a));
    }
}

// head: z = pooled@W3+b3; LN; leaky; z@W4+b4; softmax. One block per graph.
__global__ void head_kernel(const unsigned* __restrict__ pooled, const float* __restrict__ W3,
                            const float* __restrict__ b3, const float* __restrict__ g2,
                            const float* __restrict__ be2, const float* __restrict__ W4,
                            const float* __restrict__ b4, float* __restrict__ out) {
    __shared__ float prow[64];
    __shared__ float z[768];
    __shared__ float rs[4], rss[4];
    __shared__ float mu_s, rstd_s;
    __shared__ float red[10];
    int t = threadIdx.x, gI = blockIdx.x;
    if (t < 64) prow[t] = unmapf(pooled[gI * 64 + t]);
    __syncthreads();
    for (int c = t; c < 768; c += 256) {
        float acc = b3[c];
#pragma unroll 16
        for (int k = 0; k < 64; ++k) acc += prow[k] * W3[k * 768 + c];
        z[c] = acc;
    }
    __syncthreads();
    float s = 0.0f, ss = 0.0f;
    for (int c = t; c < 768; c += 256) {
        float v = z[c];
        s += v;
        ss += v * v;
    }
    for (int o = 32; o; o >>= 1) {
        s += __shfl_xor(s, o);
        ss += __shfl_xor(ss, o);
    }
    if ((t & 63) == 0) { rs[t >> 6] = s; rss[t >> 6] = ss; }
    __syncthreads();
    if (t == 0) {
        float S = rs[0] + rs[1] + rs[2] + rs[3];
        float SS = rss[0] + rss[1] + rss[2] + rss[3];
        float mu = S * (1.0f / 768.0f);
        float var = SS * (1.0f / 768.0f) - mu * mu;
        mu_s = mu;
        rstd_s = 1.0f / sqrtf(fmaxf(var, 0.0f) + 1e-5f);
    }
    __syncthreads();
    for (int c = t; c < 768; c += 256) {
        float y = (z[c] - mu_s) * rstd_s * g2[c] + be2[c];
        z[c] = lrelu(y);
    }
    if (t < 10) red[t] = 0.0f;
    __syncthreads();
    float p[10];
#pragma unroll
    for (int c = 0; c < 10; ++c) p[c] = 0.0f;
    for (int k = t; k < 768; k += 256) {
        float zv = z[k];
#pragma unroll
        for (int c = 0; c < 10; ++c) p[c] += zv * W4[k * 10 + c];
    }
#pragma unroll
    for (int c = 0; c < 10; ++c) atomicAdd(&red[c], p[c]);
    __syncthreads();
    if (t == 0) {
        float l[10], m = -1e30f;
#pragma unroll
        for (int c = 0; c < 10; ++c) {
            l[c] = red[c] + b4[c];
            m = fmaxf(m, l[c]);
        }
        float sum = 0.0f;
#pragma unroll
        for (int c = 0; c < 10; ++c) {
            l[c] = expf(l[c] - m);
            sum += l[c];
        }
        float inv = 1.0f / sum;
#pragma unroll
        for (int c = 0; c < 10; ++c) out[gI * 10 + c] = l[c] * inv;
    }
}

extern "C" void kernel_launch(void* const* d_in, const int* in_sizes, int n_in,
                              void* d_out, int out_size, void* d_ws, size_t ws_size,
                              hipStream_t stream) {
    const size_t REQUIRED = (size_t)NODES * 64 * 2      // h1 (bf16)
                          + (size_t)EDGES * 4           // csr_src
                          + (size_t)(NODES + 1) * 4     // row_ptr
                          + (size_t)NODES * 4 * 4       // cursor, deg, dinv1, dinv2
                          + (size_t)NTILES * 4 * 2      // blocksum, blockoff
                          + (size_t)NGRAPH * 64 * 4     // pooled
                          + 16;                         // flag
    if (ws_size < REQUIRED) {
        sentinel_kernel<<<20, 256, 0, stream>>>((float*)d_out, 64.0f);
        return;
    }

    const float* x = (const float*)d_in[0];
    const void* ei = d_in[1];
    const void* batch = d_in[2];
    const float* W1 = (const float*)d_in[3];
    const float* b1 = (const float*)d_in[4];
    const float* lng = (const float*)d_in[5];
    const float* lnb = (const float*)d_in[6];
    const float* W2 = (const float*)d_in[7];
    const float* b2 = (const float*)d_in[8];
    const float* W3 = (const float*)d_in[9];
    const float* b3 = (const float*)d_in[10];
    const float* g2 = (const float*)d_in[11];
    const float* be2 = (const float*)d_in[12];
    const float* W4 = (const float*)d_in[13];
    const float* b4 = (const float*)d_in[14];

    bf16* h1 = (bf16*)d_ws;                               // N*64 bf16
    int* csr_src = (int*)(h1 + (size_t)NODES * 64);       // E
    int* row_ptr = csr_src + EDGES;                       // N+1
    int* cursor = row_ptr + (NODES + 1);                  // N
    int* deg = cursor + NODES;                            // N
    float* dinv1 = (float*)(deg + NODES);                 // N
    float* dinv2 = dinv1 + NODES;                         // N
    int* blocksum = (int*)(dinv2 + NODES);                // NTILES
    int* blockoff = blocksum + NTILES;                    // NTILES
    unsigned* pooled = (unsigned*)(blockoff + NTILES);    // G*64
    int* flag = (int*)(pooled + NGRAPH * 64);             // 1

    detect_int64<<<1, 256, 0, stream>>>((const int*)ei, flag);
    hipMemsetAsync(deg, 0, (size_t)NODES * 4, stream);
    hipMemsetAsync(cursor, 0, (size_t)NODES * 4, stream);
    pooled_init<<<(NGRAPH * 64 + 255) / 256, 256, 0, stream>>>(pooled);

    // CSR build
    degree_kernel<<<(EDGES + 255) / 256, 256, 0, stream>>>(ei, flag, deg);
    dinv_kernel<<<(NODES + 255) / 256, 256, 0, stream>>>(deg, dinv1, dinv2);
    scanA<<<NTILES, 256, 0, stream>>>(deg, blocksum);
    scanB<<<1, 64, 0, stream>>>(blocksum, blockoff);
    scanC<<<NTILES, 256, 0, stream>>>(deg, blockoff, row_ptr);
    fill_csr<<<(EDGES + 255) / 256, 256, 0, stream>>>(ei, flag, row_ptr, cursor, csr_src);

    // fused layers
    gcn1_fused<<<2048, 256, 0, stream>>>(x, csr_src, row_ptr, dinv1, W1, b1, lng, lnb, h1);
    gcn2_fused<<<2048, 256, 0, stream>>>(h1, csr_src, row_ptr, dinv2, W2, b2, batch, flag,
                                         pooled);

    // head
    head_kernel<<<NGRAPH, 256, 0, stream>>>(pooled, W3, b3, g2, be2, W4, b4, (float*)d_out);
}

// Round 7
// 692.946 us; speedup vs baseline: 1.7596x; 1.1341x over previous
//
#include <hip/hip_runtime.h>
#include <hip/hip_bf16.h>

#define NODES 100000
#define EDGES 1600000
#define NGRAPH 512
#define NTILES 98  // ceil(100001 / 1024)

using bf16 = __hip_bfloat16;
typedef long long ll;

__device__ __forceinline__ float lrelu(float v) { return v > 0.0f ? v : 0.2f * v; }

__device__ __forceinline__ unsigned mapf(float f) {
    unsigned u = __float_as_uint(f);
    return (u & 0x80000000u) ? ~u : (u | 0x80000000u);
}
__device__ __forceinline__ float unmapf(unsigned u) {
    return __uint_as_float((u & 0x80000000u) ? (u ^ 0x80000000u) : ~u);
}

__device__ __forceinline__ int idx_at(const void* raw, int i, int f) {
    return f ? (int)((const ll*)raw)[i] : ((const int*)raw)[i];
}

__global__ void detect_int64(const int* __restrict__ w, int* __restrict__ flag) {
    __shared__ int red[4];
    int t = threadIdx.x;
    int v = 0;
    for (int i = t; i < 4096; i += 256) v |= w[2 * i + 1];
    for (int o = 32; o; o >>= 1) v |= __shfl_xor(v, o);
    if ((t & 63) == 0) red[t >> 6] = v;
    __syncthreads();
    if (t == 0) flag[0] = ((red[0] | red[1] | red[2] | red[3]) == 0) ? 1 : 0;
}

__global__ void sentinel_kernel(float* out, float v) {
    int i = blockIdx.x * blockDim.x + threadIdx.x;
    if (i < NGRAPH * 10) out[i] = v;
}

__global__ void pooled_init(unsigned* pooled) {
    int i = blockIdx.x * blockDim.x + threadIdx.x;
    if (i < NGRAPH * 64) pooled[i] = mapf(-1e4f);
}

// degree over dst; require BOTH endpoints valid so fill_csr fills every slot
__global__ void degree_kernel(const void* __restrict__ ei, const int* __restrict__ flag,
                              int* __restrict__ deg) {
    int i = blockIdx.x * blockDim.x + threadIdx.x;
    if (i >= EDGES) return;
    int f = flag[0];
    int s = idx_at(ei, i, f), d = idx_at(ei, EDGES + i, f);
    if ((unsigned)s < NODES && (unsigned)d < NODES) atomicAdd(&deg[d], 1);
}

__global__ void dinv_kernel(const int* __restrict__ deg, float* __restrict__ dinv1,
                            float* __restrict__ dinv2) {
    int i = blockIdx.x * blockDim.x + threadIdx.x;
    if (i < NODES) {
        float c = (float)deg[i];
        dinv1[i] = 1.0f / sqrtf(c + 2.0f);
        dinv2[i] = 1.0f / sqrtf(c + 1.0f);
    }
}

// xs[row] = x[row] * dinv1[row]  (bf16)
__global__ void prescale_x(const float* __restrict__ x, const float* __restrict__ dinv1,
                           bf16* __restrict__ xs) {
    int i = blockIdx.x * blockDim.x + threadIdx.x;
    if (i < NODES * 64) xs[i] = __float2bfloat16(x[i] * dinv1[i >> 6]);
}

// ---- exclusive scan of deg -> row_ptr ----
__global__ void scanA(const int* __restrict__ deg, int* __restrict__ blocksum) {
    __shared__ int red[4];
    int b = blockIdx.x, t = threadIdx.x;
    int base = b * 1024;
    int s = 0;
#pragma unroll
    for (int k = 0; k < 4; ++k) {
        int i = base + t + k * 256;
        if (i < NODES) s += deg[i];
    }
    for (int o = 32; o; o >>= 1) s += __shfl_xor(s, o);
    if ((t & 63) == 0) red[t >> 6] = s;
    __syncthreads();
    if (t == 0) blocksum[b] = red[0] + red[1] + red[2] + red[3];
}

__global__ void scanB(const int* __restrict__ blocksum, int* __restrict__ blockoff) {
    if (threadIdx.x == 0) {
        int acc = 0;
        for (int b = 0; b < NTILES; ++b) {
            blockoff[b] = acc;
            acc += blocksum[b];
        }
    }
}

__global__ void scanC(const int* __restrict__ deg, const int* __restrict__ blockoff,
                      int* __restrict__ row_ptr) {
    __shared__ int sc[256];
    int b = blockIdx.x, t = threadIdx.x;
    int base = b * 1024 + t * 4;
    int v[4];
#pragma unroll
    for (int k = 0; k < 4; ++k) {
        int i = base + k;
        v[k] = (i < NODES) ? deg[i] : 0;
    }
    int tsum = v[0] + v[1] + v[2] + v[3];
    sc[t] = tsum;
    __syncthreads();
    for (int o = 1; o < 256; o <<= 1) {
        int u = (t >= o) ? sc[t - o] : 0;
        __syncthreads();
        sc[t] += u;
        __syncthreads();
    }
    int excl = sc[t] - tsum + blockoff[b];
#pragma unroll
    for (int k = 0; k < 4; ++k) {
        int i = base + k;
        if (i <= NODES) row_ptr[i] = excl;
        excl += v[k];
    }
}
// ------------------------------------------

__global__ void fill_csr(const void* __restrict__ ei, const int* __restrict__ flag,
                         const int* __restrict__ row_ptr, int* __restrict__ cursor,
                         int* __restrict__ csr_src) {
    int i = blockIdx.x * blockDim.x + threadIdx.x;
    if (i >= EDGES) return;
    int f = flag[0];
    int s = idx_at(ei, i, f), d = idx_at(ei, EDGES + i, f);
    if ((unsigned)s >= NODES || (unsigned)d >= NODES) return;
    int slot = row_ptr[d] + atomicAdd(&cursor[d], 1);
    csr_src[slot] = s;
}

// gather sum of pre-scaled bf16 rows; lane-parallel index fetch + shfl broadcast
__device__ __forceinline__ float gather_rows(const bf16* __restrict__ feat,
                                             const int* __restrict__ csr, int beg, int end,
                                             int lane) {
    float acc0 = 0.0f, acc1 = 0.0f, acc2 = 0.0f, acc3 = 0.0f;
    for (int cb = beg; cb < end; cb += 64) {
        int cnt = min(64, end - cb);
        int idx = (cb + lane < end) ? csr[cb + lane] : 0;
        int j = 0;
        for (; j + 3 < cnt; j += 4) {
            int s0 = __shfl(idx, j), s1 = __shfl(idx, j + 1);
            int s2 = __shfl(idx, j + 2), s3 = __shfl(idx, j + 3);
            acc0 += __bfloat162float(feat[(size_t)s0 * 64 + lane]);
            acc1 += __bfloat162float(feat[(size_t)s1 * 64 + lane]);
            acc2 += __bfloat162float(feat[(size_t)s2 * 64 + lane]);
            acc3 += __bfloat162float(feat[(size_t)s3 * 64 + lane]);
        }
        for (; j < cnt; ++j)
            acc0 += __bfloat162float(feat[(size_t)__shfl(idx, j) * 64 + lane]);
    }
    return (acc0 + acc1) + (acc2 + acc3);
}

// fused layer1: gather(xs) + self-loop + @W1 + b1 + LN + leaky, write h1s = h1*dinv2
__global__ void gcn1_fused(const bf16* __restrict__ xs, const int* __restrict__ csr,
                           const int* __restrict__ rp, const float* __restrict__ dinv1,
                           const float* __restrict__ dinv2, const float* __restrict__ W1,
                           const float* __restrict__ b1, const float* __restrict__ lng,
                           const float* __restrict__ lnb, bf16* __restrict__ h1s) {
    __shared__ float Wl[64 * 64];
    int t = threadIdx.x;
    for (int i = t; i < 64 * 64; i += 256) Wl[i] = W1[i];
    __syncthreads();
    int lane = t & 63, wave = t >> 6;
    for (int row = blockIdx.x * 4 + wave; row < NODES; row += gridDim.x * 4) {
        float sum = gather_rows(xs, csr, rp[row], rp[row + 1], lane);
        float dv = dinv1[row];
        float self = __bfloat162float(xs[(size_t)row * 64 + lane]);
        float v = dv * (sum + 2.0f * self);
        float a = b1[lane];
#pragma unroll
        for (int k = 0; k < 64; ++k) a += __shfl(v, k) * Wl[k * 64 + lane];
        float s = a;
        for (int o = 32; o; o >>= 1) s += __shfl_xor(s, o);
        float mu = s * (1.0f / 64.0f);
        float d = a - mu;
        float q = d * d;
        for (int o = 32; o; o >>= 1) q += __shfl_xor(q, o);
        float var = q * (1.0f / 64.0f);
        float y = d / sqrtf(var + 1e-5f) * lng[lane] + lnb[lane];
        h1s[(size_t)row * 64 + lane] = __float2bfloat16(lrelu(y) * dinv2[row]);
    }
}

// fused layer2: gather(h1s) + self-loop + @W2 + b2 + leaky + max-pool
__global__ void gcn2_fused(const bf16* __restrict__ h1s, const int* __restrict__ csr,
                           const int* __restrict__ rp, const float* __restrict__ dinv2,
                           const float* __restrict__ W2, const float* __restrict__ b2,
                           const void* __restrict__ batch, const int* __restrict__ flag,
                           unsigned* __restrict__ pooled) {
    __shared__ float Wl[64 * 64];
    int t = threadIdx.x;
    for (int i = t; i < 64 * 64; i += 256) Wl[i] = W2[i];
    __syncthreads();
    int lane = t & 63, wave = t >> 6;
    int f = flag[0];
    for (int row = blockIdx.x * 4 + wave; row < NODES; row += gridDim.x * 4) {
        float sum = gather_rows(h1s, csr, rp[row], rp[row + 1], lane);
        float dv = dinv2[row];
        float self = __bfloat162float(h1s[(size_t)row * 64 + lane]);
        float v = dv * (sum + self);
        float a = b2[lane];
#pragma unroll
        for (int k = 0; k < 64; ++k) a += __shfl(v, k) * Wl[k * 64 + lane];
        a = lrelu(a);
        int g = idx_at(batch, row, f);
        if ((unsigned)g < NGRAPH) atomicMax(&pooled[g * 64 + lane], mapf(a));
    }
}

// head: z = pooled@W3+b3; LN; leaky; z@W4+b4; softmax. One block per graph.
__global__ void head_kernel(const unsigned* __restrict__ pooled, const float* __restrict__ W3,
                            const float* __restrict__ b3, const float* __restrict__ g2,
                            const float* __restrict__ be2, const float* __restrict__ W4,
                            const float* __restrict__ b4, float* __restrict__ out) {
    __shared__ float prow[64];
    __shared__ float z[768];
    __shared__ float rs[4], rss[4];
    __shared__ float mu_s, rstd_s;
    __shared__ float red[10];
    int t = threadIdx.x, gI = blockIdx.x;
    if (t < 64) prow[t] = unmapf(pooled[gI * 64 + t]);
    __syncthreads();
    for (int c = t; c < 768; c += 256) {
        float acc = b3[c];
#pragma unroll 16
        for (int k = 0; k < 64; ++k) acc += prow[k] * W3[k * 768 + c];
        z[c] = acc;
    }
    __syncthreads();
    float s = 0.0f, ss = 0.0f;
    for (int c = t; c < 768; c += 256) {
        float v = z[c];
        s += v;
        ss += v * v;
    }
    for (int o = 32; o; o >>= 1) {
        s += __shfl_xor(s, o);
        ss += __shfl_xor(ss, o);
    }
    if ((t & 63) == 0) { rs[t >> 6] = s; rss[t >> 6] = ss; }
    __syncthreads();
    if (t == 0) {
        float S = rs[0] + rs[1] + rs[2] + rs[3];
        float SS = rss[0] + rss[1] + rss[2] + rss[3];
        float mu = S * (1.0f / 768.0f);
        float var = SS * (1.0f / 768.0f) - mu * mu;
        mu_s = mu;
        rstd_s = 1.0f / sqrtf(fmaxf(var, 0.0f) + 1e-5f);
    }
    __syncthreads();
    for (int c = t; c < 768; c += 256) {
        float y = (z[c] - mu_s) * rstd_s * g2[c] + be2[c];
        z[c] = lrelu(y);
    }
    if (t < 10) red[t] = 0.0f;
    __syncthreads();
    float p[10];
#pragma unroll
    for (int c = 0; c < 10; ++c) p[c] = 0.0f;
    for (int k = t; k < 768; k += 256) {
        float zv = z[k];
#pragma unroll
        for (int c = 0; c < 10; ++c) p[c] += zv * W4[k * 10 + c];
    }
#pragma unroll
    for (int c = 0; c < 10; ++c) atomicAdd(&red[c], p[c]);
    __syncthreads();
    if (t == 0) {
        float l[10], m = -1e30f;
#pragma unroll
        for (int c = 0; c < 10; ++c) {
            l[c] = red[c] + b4[c];
            m = fmaxf(m, l[c]);
        }
        float sum = 0.0f;
#pragma unroll
        for (int c = 0; c < 10; ++c) {
            l[c] = expf(l[c] - m);
            sum += l[c];
        }
        float inv = 1.0f / sum;
#pragma unroll
        for (int c = 0; c < 10; ++c) out[gI * 10 + c] = l[c] * inv;
    }
}

extern "C" void kernel_launch(void* const* d_in, const int* in_sizes, int n_in,
                              void* d_out, int out_size, void* d_ws, size_t ws_size,
                              hipStream_t stream) {
    const size_t REQUIRED = (size_t)NODES * 64 * 2 * 2  // xs + h1s (bf16)
                          + (size_t)EDGES * 4           // csr_src
                          + (size_t)(NODES + 1) * 4     // row_ptr
                          + (size_t)NODES * 4 * 4       // cursor, deg, dinv1, dinv2
                          + (size_t)NTILES * 4 * 2      // blocksum, blockoff
                          + (size_t)NGRAPH * 64 * 4     // pooled
                          + 16;                         // flag
    if (ws_size < REQUIRED) {
        sentinel_kernel<<<20, 256, 0, stream>>>((float*)d_out, 64.0f);
        return;
    }

    const float* x = (const float*)d_in[0];
    const void* ei = d_in[1];
    const void* batch = d_in[2];
    const float* W1 = (const float*)d_in[3];
    const float* b1 = (const float*)d_in[4];
    const float* lng = (const float*)d_in[5];
    const float* lnb = (const float*)d_in[6];
    const float* W2 = (const float*)d_in[7];
    const float* b2 = (const float*)d_in[8];
    const float* W3 = (const float*)d_in[9];
    const float* b3 = (const float*)d_in[10];
    const float* g2 = (const float*)d_in[11];
    const float* be2 = (const float*)d_in[12];
    const float* W4 = (const float*)d_in[13];
    const float* b4 = (const float*)d_in[14];

    bf16* xs = (bf16*)d_ws;                               // N*64 bf16
    bf16* h1s = xs + (size_t)NODES * 64;                  // N*64 bf16
    int* csr_src = (int*)(h1s + (size_t)NODES * 64);      // E
    int* row_ptr = csr_src + EDGES;                       // N+1
    int* cursor = row_ptr + (NODES + 1);                  // N
    int* deg = cursor + NODES;                            // N
    float* dinv1 = (float*)(deg + NODES);                 // N
    float* dinv2 = dinv1 + NODES;                         // N
    int* blocksum = (int*)(dinv2 + NODES);                // NTILES
    int* blockoff = blocksum + NTILES;                    // NTILES
    unsigned* pooled = (unsigned*)(blockoff + NTILES);    // G*64
    int* flag = (int*)(pooled + NGRAPH * 64);             // 1

    detect_int64<<<1, 256, 0, stream>>>((const int*)ei, flag);
    hipMemsetAsync(deg, 0, (size_t)NODES * 4, stream);
    hipMemsetAsync(cursor, 0, (size_t)NODES * 4, stream);
    pooled_init<<<(NGRAPH * 64 + 255) / 256, 256, 0, stream>>>(pooled);

    // CSR build
    degree_kernel<<<(EDGES + 255) / 256, 256, 0, stream>>>(ei, flag, deg);
    dinv_kernel<<<(NODES + 255) / 256, 256, 0, stream>>>(deg, dinv1, dinv2);
    prescale_x<<<(NODES * 64 + 255) / 256, 256, 0, stream>>>(x, dinv1, xs);
    scanA<<<NTILES, 256, 0, stream>>>(deg, blocksum);
    scanB<<<1, 64, 0, stream>>>(blocksum, blockoff);
    scanC<<<NTILES, 256, 0, stream>>>(deg, blockoff, row_ptr);
    fill_csr<<<(EDGES + 255) / 256, 256, 0, stream>>>(ei, flag, row_ptr, cursor, csr_src);

    // fused layers
    gcn1_fused<<<2048, 256, 0, stream>>>(xs, csr_src, row_ptr, dinv1, dinv2, W1, b1, lng,
                                         lnb, h1s);
    gcn2_fused<<<2048, 256, 0, stream>>>(h1s, csr_src, row_ptr, dinv2, W2, b2, batch, flag,
                                         pooled);

    // head
    head_kernel<<<NGRAPH, 256, 0, stream>>>(pooled, W3, b3, g2, be2, W4, b4, (float*)d_out);
}